// Round 1
// baseline (136.658 us; speedup 1.0000x reference)
//
#include <hip/hip_runtime.h>

#define NN 64
#define HH 512

typedef _Float16 h8 __attribute__((ext_vector_type(8)));
typedef float    fx4 __attribute__((ext_vector_type(4)));

#define MFMA __builtin_amdgcn_mfma_f32_16x16x32_f16

// ---------------------------------------------------------------------------
// ws layout (bytes):
//   [0,        4 MiB)  W1h : per node n, [512][64] fp16  (same linear layout as W1)
//   [4 MiB,    8 MiB)  W2h : per node n, [64][512] fp16  (same linear layout as W2)
//   [8 MiB,   12 MiB)  W3h : per node n, [512][64] fp16  (cols 0..63 of W3 only)
//   [12 MiB, +128 KiB) w3c : per node n, [512] fp32 = W3n[h][64+n]  (pre-gathered)
// total = 12,713,984 B
// ---------------------------------------------------------------------------
#define WS_NEEDED 12713984ull

__global__ __launch_bounds__(256)
void cvt_wts(const float* __restrict__ W1, const float* __restrict__ W2,
             const float* __restrict__ W3, char* __restrict__ ws)
{
    _Float16* o1 = (_Float16*)ws;
    _Float16* o2 = o1 + 2097152;
    _Float16* o3 = o2 + 2097152;
    float*    oc = (float*)(ws + 12582912);
    const int g = blockIdx.x * 256 + threadIdx.x;   // 0 .. 262143, one 8-float block each

    // W1: layout-preserving stream convert
    {
        const float* s = W1 + (size_t)g * 8;
        float4 a = *(const float4*)s, b = *(const float4*)(s + 4);
        h8 h;
        h[0]=(_Float16)a.x; h[1]=(_Float16)a.y; h[2]=(_Float16)a.z; h[3]=(_Float16)a.w;
        h[4]=(_Float16)b.x; h[5]=(_Float16)b.y; h[6]=(_Float16)b.z; h[7]=(_Float16)b.w;
        *(h8*)(o1 + (size_t)g * 8) = h;
    }
    // W2: layout-preserving stream convert
    {
        const float* s = W2 + (size_t)g * 8;
        float4 a = *(const float4*)s, b = *(const float4*)(s + 4);
        h8 h;
        h[0]=(_Float16)a.x; h[1]=(_Float16)a.y; h[2]=(_Float16)a.z; h[3]=(_Float16)a.w;
        h[4]=(_Float16)b.x; h[5]=(_Float16)b.y; h[6]=(_Float16)b.z; h[7]=(_Float16)b.w;
        *(h8*)(o2 + (size_t)g * 8) = h;
    }
    // W3 cols 0..63: out[n][h][k] = W3[n][h][k], k < 64
    {
        const int n3 = g >> 12;
        const int h3 = (g >> 3) & 511;
        const int k3 = (g & 7) * 8;
        const float* s = W3 + (size_t)n3 * 65536 + h3 * 128 + k3;
        float4 a = *(const float4*)s, b = *(const float4*)(s + 4);
        h8 h;
        h[0]=(_Float16)a.x; h[1]=(_Float16)a.y; h[2]=(_Float16)a.z; h[3]=(_Float16)a.w;
        h[4]=(_Float16)b.x; h[5]=(_Float16)b.y; h[6]=(_Float16)b.z; h[7]=(_Float16)b.w;
        *(h8*)(o3 + (size_t)g * 8) = h;
    }
    // w3c gather: oc[n][h] = W3[n][h][64+n]   (done once here instead of 8x per node)
    if (g < 32768) {
        const int n3 = g >> 9;
        const int h3 = g & 511;
        oc[g] = W3[(size_t)n3 * 65536 + (size_t)h3 * 128 + 64 + n3];
    }
}

// ---------------------------------------------------------------------------
// Main kernel: WG = 256 thr (4 waves), node n = bid&63 (same-node WGs share an
// XCD), batch rows [tile*128, +128), wave owns 32 rows. Weights are fp16 in ws
// and L2-resident (1.5 MB / XCD) -> B-fragments read DIRECTLY global->VGPR:
// no weight LDS, no cvt, single barrier after scalar prologue.
// LDS holds only the per-wave h1/r1 transpose buffer + scalar arrays.
// ---------------------------------------------------------------------------
__global__ __launch_bounds__(256, 2)
void causal_mfma4(const float* __restrict__ x, const char* __restrict__ ws,
                  const float* __restrict__ b3, const float* __restrict__ W4,
                  const float* __restrict__ b4, float* __restrict__ out)
{
    __shared__ __align__(16) char smem[25088];
    _Float16* priv = (_Float16*)smem;            // [4 waves][32][72]
    float*    w3cs = (float*)(smem + 18432);     // [512]
    float*    b3s  = w3cs + 512;                 // [512]
    float*    w4s  = b3s + 512;                  // [512]
    float*    xns  = w4s + 512;                  // [128]

    const int tid  = threadIdx.x;
    const int bid  = blockIdx.x;
    const int n    = bid & 63;
    const int tile = bid >> 6;                   // 0..7
    const int lane = tid & 63;
    const int pos  = lane & 15;
    const int quad = lane >> 4;
    const int wv   = __builtin_amdgcn_readfirstlane(tid >> 6);
    const int row0 = tile * 128;
    const int wrow = wv << 5;

    const _Float16* W1h  = (const _Float16*)ws + (size_t)n * 32768;
    const _Float16* W2h  = (const _Float16*)ws + 2097152 + (size_t)n * 32768;
    const _Float16* W3h  = (const _Float16*)ws + 4194304 + (size_t)n * 32768;
    const float*    w3cp = (const float*)(ws + 12582912) + n * 512;

    // ---- prologue: scalar arrays + xn ----
    #pragma unroll
    for (int k = 0; k < 2; ++k) {
        const int h = tid + k * 256;
        w3cs[h] = w3cp[h];
        b3s[h]  = b3[n * HH + h];
        w4s[h]  = W4[n * HH + h];
    }
    if (tid < 128) xns[tid] = x[(size_t)(row0 + tid) * NN + n];

    // Xm A-fragments (own element zeroed) — chunk-invariant
    h8 aX[2][2];
    #pragma unroll
    for (int mt = 0; mt < 2; ++mt)
        #pragma unroll
        for (int ks = 0; ks < 2; ++ks) {
            const float* p = x + (size_t)(row0 + wrow + mt * 16 + pos) * NN + ks * 32 + quad * 8;
            float4 a = *(const float4*)p, bq = *(const float4*)(p + 4);
            float v[8] = {a.x, a.y, a.z, a.w, bq.x, bq.y, bq.z, bq.w};
            const int base = ks * 32 + quad * 8;
            #pragma unroll
            for (int j = 0; j < 8; ++j) if (base + j == n) v[j] = 0.f;
            h8 h;
            #pragma unroll
            for (int j = 0; j < 8; ++j) h[j] = (_Float16)v[j];
            aX[mt][ks] = h;
        }
    __syncthreads();                              // the ONLY barrier

    _Float16* P = priv + wv * 2304;               // own 32x72 buffer

    // ---- fused stages A+B over 8 h-chunks of 64 (no barriers, frags from L2) ----
    fx4 acc2[2][4] = {};
    #pragma unroll 2
    for (int c = 0; c < 8; ++c) {
        const int hc = c << 6;
        // stage A: h1 chunk = Xm @ W1chunk^T
        fx4 accA[2][4] = {};
        #pragma unroll
        for (int ks = 0; ks < 2; ++ks)
            #pragma unroll
            for (int nt = 0; nt < 4; ++nt) {
                h8 bf = *(const h8*)(W1h + (hc + nt * 16 + pos) * 64 + ks * 32 + quad * 8);
                accA[0][nt] = MFMA(aX[0][ks], bf, accA[0][nt], 0, 0, 0);
                accA[1][nt] = MFMA(aX[1][ks], bf, accA[1][nt], 0, 0, 0);
            }
        // h1 -> own LDS (relu, fp16), then A-frags for stage B
        #pragma unroll
        for (int mt = 0; mt < 2; ++mt)
            #pragma unroll
            for (int nt = 0; nt < 4; ++nt)
                #pragma unroll
                for (int r = 0; r < 4; ++r)
                    P[(mt * 16 + quad * 4 + r) * 72 + nt * 16 + pos] =
                        (_Float16)fmaxf(accA[mt][nt][r], 0.f);
        h8 aH[2][2];
        #pragma unroll
        for (int mt = 0; mt < 2; ++mt)
            #pragma unroll
            for (int ks = 0; ks < 2; ++ks)
                aH[mt][ks] = *(const h8*)(P + (mt * 16 + pos) * 72 + ks * 32 + quad * 8);
        // stage B: acc2 += h1chunk @ W2chunk^T
        #pragma unroll
        for (int ks = 0; ks < 2; ++ks)
            #pragma unroll
            for (int cm = 0; cm < 4; ++cm) {
                h8 bf = *(const h8*)(W2h + (cm * 16 + pos) * 512 + hc + ks * 32 + quad * 8);
                acc2[0][cm] = MFMA(aH[0][ks], bf, acc2[0][cm], 0, 0, 0);
                acc2[1][cm] = MFMA(aH[1][ks], bf, acc2[1][cm], 0, 0, 0);
            }
    }

    // ---- r1 -> own LDS (relu), read back as A-frags ----
    #pragma unroll
    for (int mt = 0; mt < 2; ++mt)
        #pragma unroll
        for (int cm = 0; cm < 4; ++cm)
            #pragma unroll
            for (int r = 0; r < 4; ++r)
                P[(mt * 16 + quad * 4 + r) * 72 + cm * 16 + pos] =
                    (_Float16)fmaxf(acc2[mt][cm][r], 0.f);
    h8 aR[2][2];
    #pragma unroll
    for (int mt = 0; mt < 2; ++mt)
        #pragma unroll
        for (int ks = 0; ks < 2; ++ks)
            aR[mt][ks] = *(const h8*)(P + (mt * 16 + pos) * 72 + ks * 32 + quad * 8);
    // fold A-frag: k=64 -> xn, k=65 -> 1 (only quad 0 lanes carry data)
    h8 af3[2];
    #pragma unroll
    for (int mt = 0; mt < 2; ++mt) {
        h8 h;
        #pragma unroll
        for (int j = 0; j < 8; ++j) h[j] = (_Float16)0.f;
        if (quad == 0) { h[0] = (_Float16)xns[wrow + mt * 16 + pos]; h[1] = (_Float16)1.f; }
        af3[mt] = h;
    }

    // ---- stage C/D over 8 h-chunks (frags from L2, no barriers) ----
    float o[2][4] = {};
    #pragma unroll 2
    for (int c = 0; c < 8; ++c) {
        const int hc = c << 6;
        fx4 acc3[2][4] = {};
        #pragma unroll
        for (int ks = 0; ks < 2; ++ks)
            #pragma unroll
            for (int nt = 0; nt < 4; ++nt) {
                h8 bf = *(const h8*)(W3h + (hc + nt * 16 + pos) * 64 + ks * 32 + quad * 8);
                acc3[0][nt] = MFMA(aR[0][ks], bf, acc3[0][nt], 0, 0, 0);
                acc3[1][nt] = MFMA(aR[1][ks], bf, acc3[1][nt], 0, 0, 0);
            }
        // fold: += [xn,1] @ [w3c; b3]
        #pragma unroll
        for (int nt = 0; nt < 4; ++nt) {
            h8 bf3;
            #pragma unroll
            for (int j = 0; j < 8; ++j) bf3[j] = (_Float16)0.f;
            if (quad == 0) {
                const int h = hc + nt * 16 + pos;
                bf3[0] = (_Float16)w3cs[h];
                bf3[1] = (_Float16)b3s[h];
            }
            acc3[0][nt] = MFMA(af3[0], bf3, acc3[0][nt], 0, 0, 0);
            acc3[1][nt] = MFMA(af3[1], bf3, acc3[1][nt], 0, 0, 0);
        }
        // relu + W4 dot
        #pragma unroll
        for (int nt = 0; nt < 4; ++nt) {
            const float w4v = w4s[hc + nt * 16 + pos];
            #pragma unroll
            for (int mt = 0; mt < 2; ++mt)
                #pragma unroll
                for (int r = 0; r < 4; ++r)
                    o[mt][r] = fmaf(fmaxf(acc3[mt][nt][r], 0.f), w4v, o[mt][r]);
        }
    }

    // ---- reduce over the 16 h-columns (pos bits), store ----
    #pragma unroll
    for (int m = 1; m < 16; m <<= 1)
        #pragma unroll
        for (int mt = 0; mt < 2; ++mt)
            #pragma unroll
            for (int r = 0; r < 4; ++r)
                o[mt][r] += __shfl_xor(o[mt][r], m, 64);

    if (pos == 0) {
        const float bb = b4[n];
        #pragma unroll
        for (int mt = 0; mt < 2; ++mt)
            #pragma unroll
            for (int r = 0; r < 4; ++r) {
                const int row = row0 + wrow + mt * 16 + quad * 4 + r;
                out[(size_t)row * 64 + n] = fmaxf(o[mt][r] + bb, 0.f);
            }
    }
}

// ---------------------------------------------------------------------------
// Legacy fallback (the proven 112 µs kernel) — used only if ws is too small.
// ---------------------------------------------------------------------------
__device__ __forceinline__ void cvt_store16(_Float16* d, const float4* p) {
    h8 h0, h1;
    h0[0]=(_Float16)p[0].x; h0[1]=(_Float16)p[0].y; h0[2]=(_Float16)p[0].z; h0[3]=(_Float16)p[0].w;
    h0[4]=(_Float16)p[1].x; h0[5]=(_Float16)p[1].y; h0[6]=(_Float16)p[1].z; h0[7]=(_Float16)p[1].w;
    h1[0]=(_Float16)p[2].x; h1[1]=(_Float16)p[2].y; h1[2]=(_Float16)p[2].z; h1[3]=(_Float16)p[2].w;
    h1[4]=(_Float16)p[3].x; h1[5]=(_Float16)p[3].y; h1[6]=(_Float16)p[3].z; h1[7]=(_Float16)p[3].w;
    *(h8*)d = h0; *((h8*)d + 1) = h1;
}

__global__ __launch_bounds__(256, 2)
void causal_mfma3(const float* __restrict__ x,  const float* __restrict__ W1,
                  const float* __restrict__ W2, const float* __restrict__ W3,
                  const float* __restrict__ b3, const float* __restrict__ W4,
                  const float* __restrict__ b4, float* __restrict__ out)
{
    __shared__ __align__(16) char smem[61952];
    _Float16* W1c  = (_Float16*)smem;
    _Float16* W2c  = W1c + 2 * 4608;
    _Float16* priv = W2c + 2 * 4608;
    float*    w3cs = (float*)(smem + 55296);
    float*    b3s  = w3cs + 512;
    float*    w4s  = b3s + 512;
    float*    xns  = w4s + 512;

    const int tid  = threadIdx.x;
    const int bid  = blockIdx.x;
    const int n    = bid & 63;
    const int tile = bid >> 6;
    const int lane = tid & 63;
    const int pos  = lane & 15;
    const int quad = lane >> 4;
    const int wv   = __builtin_amdgcn_readfirstlane(tid >> 6);
    const int row0 = tile * 128;
    const int wrow = wv << 5;

    const float* W1n = W1 + (size_t)n * HH * NN;
    const float* W2n = W2 + (size_t)n * NN * HH;
    const float* W3n = W3 + (size_t)n * HH * 128;

    const int trow = tid >> 2;
    const int tcol = (tid & 3) << 4;

    {
        float4 p1[4], p2[4];
        #pragma unroll
        for (int q = 0; q < 4; ++q) p1[q] = *(const float4*)(W1n + trow * 64 + tcol + q * 4);
        #pragma unroll
        for (int q = 0; q < 4; ++q) p2[q] = *(const float4*)(W2n + (size_t)trow * HH + tcol + q * 4);
        #pragma unroll
        for (int k = 0; k < 2; ++k) {
            const int h = tid + k * 256;
            w3cs[h] = W3n[(size_t)h * 128 + 64 + n];
            b3s[h]  = b3[n * HH + h];
            w4s[h]  = W4[n * HH + h];
        }
        if (tid < 128) xns[tid] = x[(size_t)(row0 + tid) * NN + n];
        cvt_store16(W1c + trow * 72 + tcol, p1);
        cvt_store16(W2c + trow * 72 + tcol, p2);
    }

    h8 aX[2][2];
    #pragma unroll
    for (int mt = 0; mt < 2; ++mt)
        #pragma unroll
        for (int ks = 0; ks < 2; ++ks) {
            const float* p = x + (size_t)(row0 + wrow + mt * 16 + pos) * NN + ks * 32 + quad * 8;
            float4 a = *(const float4*)p, bq = *(const float4*)(p + 4);
            float v[8] = {a.x, a.y, a.z, a.w, bq.x, bq.y, bq.z, bq.w};
            const int base = ks * 32 + quad * 8;
            #pragma unroll
            for (int j = 0; j < 8; ++j) if (base + j == n) v[j] = 0.f;
            h8 h;
            #pragma unroll
            for (int j = 0; j < 8; ++j) h[j] = (_Float16)v[j];
            aX[mt][ks] = h;
        }
    __syncthreads();

    _Float16* P = priv + wv * 2304;

    fx4 acc2[2][4] = {};
    for (int c = 0; c < 8; ++c) {
        const int cb = c & 1;
        float4 p1[4], p2[4];
        if (c < 7) {
            const int hb1 = (c + 1) << 6;
            #pragma unroll
            for (int q = 0; q < 4; ++q) p1[q] = *(const float4*)(W1n + (hb1 + trow) * 64 + tcol + q * 4);
            #pragma unroll
            for (int q = 0; q < 4; ++q) p2[q] = *(const float4*)(W2n + (size_t)trow * HH + hb1 + tcol + q * 4);
        }
        const _Float16* W1L = W1c + cb * 4608;
        fx4 accA[2][4] = {};
        #pragma unroll
        for (int ks = 0; ks < 2; ++ks)
            #pragma unroll
            for (int nt = 0; nt < 4; ++nt) {
                h8 bf = *(const h8*)(W1L + (nt * 16 + pos) * 72 + ks * 32 + quad * 8);
                accA[0][nt] = MFMA(aX[0][ks], bf, accA[0][nt], 0, 0, 0);
                accA[1][nt] = MFMA(aX[1][ks], bf, accA[1][nt], 0, 0, 0);
            }
        #pragma unroll
        for (int mt = 0; mt < 2; ++mt)
            #pragma unroll
            for (int nt = 0; nt < 4; ++nt)
                #pragma unroll
                for (int r = 0; r < 4; ++r)
                    P[(mt * 16 + quad * 4 + r) * 72 + nt * 16 + pos] =
                        (_Float16)fmaxf(accA[mt][nt][r], 0.f);
        h8 aH[2][2];
        #pragma unroll
        for (int mt = 0; mt < 2; ++mt)
            #pragma unroll
            for (int ks = 0; ks < 2; ++ks)
                aH[mt][ks] = *(const h8*)(P + (mt * 16 + pos) * 72 + ks * 32 + quad * 8);
        const _Float16* W2L = W2c + cb * 4608;
        #pragma unroll
        for (int ks = 0; ks < 2; ++ks)
            #pragma unroll
            for (int cm = 0; cm < 4; ++cm) {
                h8 bf = *(const h8*)(W2L + (cm * 16 + pos) * 72 + ks * 32 + quad * 8);
                acc2[0][cm] = MFMA(aH[0][ks], bf, acc2[0][cm], 0, 0, 0);
                acc2[1][cm] = MFMA(aH[1][ks], bf, acc2[1][cm], 0, 0, 0);
            }
        if (c < 7) {
            cvt_store16(W1c + (cb ^ 1) * 4608 + trow * 72 + tcol, p1);
            cvt_store16(W2c + (cb ^ 1) * 4608 + trow * 72 + tcol, p2);
        }
        __syncthreads();
    }

    #pragma unroll
    for (int mt = 0; mt < 2; ++mt)
        #pragma unroll
        for (int cm = 0; cm < 4; ++cm)
            #pragma unroll
            for (int r = 0; r < 4; ++r)
                P[(mt * 16 + quad * 4 + r) * 72 + cm * 16 + pos] =
                    (_Float16)fmaxf(acc2[mt][cm][r], 0.f);
    h8 aR[2][2];
    #pragma unroll
    for (int mt = 0; mt < 2; ++mt)
        #pragma unroll
        for (int ks = 0; ks < 2; ++ks)
            aR[mt][ks] = *(const h8*)(P + (mt * 16 + pos) * 72 + ks * 32 + quad * 8);
    h8 af3[2];
    #pragma unroll
    for (int mt = 0; mt < 2; ++mt) {
        h8 h;
        #pragma unroll
        for (int j = 0; j < 8; ++j) h[j] = (_Float16)0.f;
        if (quad == 0) { h[0] = (_Float16)xns[wrow + mt * 16 + pos]; h[1] = (_Float16)1.f; }
        af3[mt] = h;
    }

    {
        float4 p3[4];
        #pragma unroll
        for (int q = 0; q < 4; ++q) p3[q] = *(const float4*)(W3n + (size_t)trow * 128 + tcol + q * 4);
        cvt_store16(W1c + trow * 72 + tcol, p3);
    }
    __syncthreads();

    float o[2][4] = {};
    for (int c = 0; c < 8; ++c) {
        const int cb = c & 1;
        const int hc = c << 6;
        float4 p3[4];
        if (c < 7) {
            #pragma unroll
            for (int q = 0; q < 4; ++q)
                p3[q] = *(const float4*)(W3n + (size_t)(hc + 64 + trow) * 128 + tcol + q * 4);
        }
        const _Float16* W3L = W1c + cb * 4608;
        fx4 acc3[2][4] = {};
        #pragma unroll
        for (int ks = 0; ks < 2; ++ks)
            #pragma unroll
            for (int nt = 0; nt < 4; ++nt) {
                h8 bf = *(const h8*)(W3L + (nt * 16 + pos) * 72 + ks * 32 + quad * 8);
                acc3[0][nt] = MFMA(aR[0][ks], bf, acc3[0][nt], 0, 0, 0);
                acc3[1][nt] = MFMA(aR[1][ks], bf, acc3[1][nt], 0, 0, 0);
            }
        #pragma unroll
        for (int nt = 0; nt < 4; ++nt) {
            h8 bf3;
            #pragma unroll
            for (int j = 0; j < 8; ++j) bf3[j] = (_Float16)0.f;
            if (quad == 0) {
                const int h = hc + nt * 16 + pos;
                bf3[0] = (_Float16)w3cs[h];
                bf3[1] = (_Float16)b3s[h];
            }
            acc3[0][nt] = MFMA(af3[0], bf3, acc3[0][nt], 0, 0, 0);
            acc3[1][nt] = MFMA(af3[1], bf3, acc3[1][nt], 0, 0, 0);
        }
        #pragma unroll
        for (int nt = 0; nt < 4; ++nt) {
            const float w4v = w4s[hc + nt * 16 + pos];
            #pragma unroll
            for (int mt = 0; mt < 2; ++mt)
                #pragma unroll
                for (int r = 0; r < 4; ++r)
                    o[mt][r] = fmaf(fmaxf(acc3[mt][nt][r], 0.f), w4v, o[mt][r]);
        }
        if (c < 7) cvt_store16(W1c + (cb ^ 1) * 4608 + trow * 72 + tcol, p3);
        __syncthreads();
    }

    #pragma unroll
    for (int m = 1; m < 16; m <<= 1)
        #pragma unroll
        for (int mt = 0; mt < 2; ++mt)
            #pragma unroll
            for (int r = 0; r < 4; ++r)
                o[mt][r] += __shfl_xor(o[mt][r], m, 64);

    if (pos == 0) {
        const float bb = b4[n];
        #pragma unroll
        for (int mt = 0; mt < 2; ++mt)
            #pragma unroll
            for (int r = 0; r < 4; ++r) {
                const int row = row0 + wrow + mt * 16 + quad * 4 + r;
                out[(size_t)row * 64 + n] = fmaxf(o[mt][r] + bb, 0.f);
            }
    }
}

extern "C" void kernel_launch(void* const* d_in, const int* in_sizes, int n_in,
                              void* d_out, int out_size, void* d_ws, size_t ws_size,
                              hipStream_t stream)
{
    const float* x  = (const float*)d_in[0];
    const float* W1 = (const float*)d_in[1];
    const float* W2 = (const float*)d_in[2];
    const float* W3 = (const float*)d_in[3];
    const float* b3 = (const float*)d_in[4];
    const float* W4 = (const float*)d_in[5];
    const float* b4 = (const float*)d_in[6];
    float* out = (float*)d_out;

    if (d_ws != nullptr && ws_size >= WS_NEEDED) {
        hipLaunchKernelGGL(cvt_wts, dim3(1024), dim3(256), 0, stream,
                           W1, W2, W3, (char*)d_ws);
        hipLaunchKernelGGL(causal_mfma4, dim3(512), dim3(256), 0, stream,
                           x, (const char*)d_ws, b3, W4, b4, out);
    } else {
        hipLaunchKernelGGL(causal_mfma3, dim3(512), dim3(256), 0, stream,
                           x, W1, W2, W3, b3, W4, b4, out);
    }
}

// Round 2
// 112.668 us; speedup vs baseline: 1.2129x; 1.2129x over previous
//
#include <hip/hip_runtime.h>

#define NN 64
#define HH 512

typedef _Float16 h8 __attribute__((ext_vector_type(8)));
typedef float    fx4 __attribute__((ext_vector_type(4)));

#define MFMA __builtin_amdgcn_mfma_f32_16x16x32_f16

// ---------------------------------------------------------------------------
// ws layout (bytes):
//   [0,        4 MiB)  W1f : per node, frag-ordered fp16 [8 chunks][2 ks][4 nt][64 lane][8]
//   [4 MiB,    8 MiB)  W2f : same shape (frag for stage B)
//   [8 MiB,   12 MiB)  W3f : same shape (cols 0..63 of W3)
//   [12 MiB, +128 KiB) w3c : per node, [512] fp32 = W3n[h][64+n] (pre-gathered)
// total = 12,713,984 B
// ---------------------------------------------------------------------------
#define WS_NEEDED 12713984ull

typedef __attribute__((address_space(1))) const unsigned int gu32;
typedef __attribute__((address_space(3))) unsigned int       lu32;

__device__ __forceinline__ void gld16(const void* g, void* l) {
    // DMA 16B/lane global->LDS; LDS dest = wave-uniform base + lane*16
    __builtin_amdgcn_global_load_lds((gu32*)g, (lu32*)l, 16, 0, 0);
}

__device__ __forceinline__ h8 cvt8(const float* __restrict__ s) {
    float4 a = *(const float4*)s, b = *(const float4*)(s + 4);
    h8 h;
    h[0]=(_Float16)a.x; h[1]=(_Float16)a.y; h[2]=(_Float16)a.z; h[3]=(_Float16)a.w;
    h[4]=(_Float16)b.x; h[5]=(_Float16)b.y; h[6]=(_Float16)b.z; h[7]=(_Float16)b.w;
    return h;
}

// One thread per 16B output block in each of W1f/W2f/W3f.
// Block id g decodes as [n:6][c:3][ks:1][nt:2][lane:6].
__global__ __launch_bounds__(256)
void cvt_frag(const float* __restrict__ W1, const float* __restrict__ W2,
              const float* __restrict__ W3, char* __restrict__ ws)
{
    const int g    = blockIdx.x * 256 + threadIdx.x;   // 0 .. 262143
    const int n    = g >> 12;
    const int c    = (g >> 9) & 7;
    const int ks   = (g >> 8) & 1;
    const int nt   = (g >> 6) & 3;
    const int l    = g & 63;
    const int pos  = l & 15;
    const int quad = l >> 4;

    _Float16* o1 = (_Float16*)ws;
    _Float16* o2 = o1 + 2097152;
    _Float16* o3 = o2 + 2097152;
    float*    oc = (float*)(ws + 12582912);

    // W1 frag: bf[j] = W1[n][c*64 + nt*16 + pos][ks*32 + quad*8 + j]
    {
        const float* s = W1 + (size_t)n * 32768
                            + (size_t)(c * 64 + nt * 16 + pos) * 64
                            + ks * 32 + quad * 8;
        *(h8*)(o1 + (size_t)g * 8) = cvt8(s);
    }
    // W2 frag: bf[j] = W2[n][nt*16 + pos][c*64 + ks*32 + quad*8 + j]
    {
        const float* s = W2 + (size_t)n * 32768
                            + (size_t)(nt * 16 + pos) * 512
                            + c * 64 + ks * 32 + quad * 8;
        *(h8*)(o2 + (size_t)g * 8) = cvt8(s);
    }
    // W3 frag (cols < 64): bf[j] = W3[n][c*64 + nt*16 + pos][ks*32 + quad*8 + j]
    {
        const float* s = W3 + (size_t)n * 65536
                            + (size_t)(c * 64 + nt * 16 + pos) * 128
                            + ks * 32 + quad * 8;
        *(h8*)(o3 + (size_t)g * 8) = cvt8(s);
    }
    // w3c gather: oc[n][h] = W3[n][h][64+n]
    if (g < 32768) {
        const int n3 = g >> 9;
        const int h3 = g & 511;
        oc[g] = W3[(size_t)n3 * 65536 + (size_t)h3 * 128 + 64 + n3];
    }
}

// ---------------------------------------------------------------------------
// Main kernel: WG = 256 thr (4 waves), node n = bid&63, batch rows
// [tile*128,+128), wave owns 32 rows. fp16 frag-ordered weights staged
// global->LDS via global_load_lds dwordx4, double-buffered (m97 pattern).
// Frag reads are lane-contiguous ds_read_b128 (conflict-free).
// ---------------------------------------------------------------------------
__global__ __launch_bounds__(256, 2)
void causal_mfma5(const float* __restrict__ x, const char* __restrict__ ws,
                  const float* __restrict__ b3, const float* __restrict__ W4,
                  const float* __restrict__ b4, float* __restrict__ out)
{
    __shared__ __align__(16) char smem[57856];
    _Float16* w1b  = (_Float16*)smem;            // [2][4096] fp16 (dbuf chunk; stage C reuses for W3)
    _Float16* w2b  = w1b + 8192;                 // [2][4096] fp16
    _Float16* priv = w2b + 8192;                 // [4 waves][32][72] fp16
    float*    w3cs = (float*)(smem + 51200);     // [512]
    float*    b3s  = w3cs + 512;                 // [512]
    float*    w4s  = b3s + 512;                  // [512]
    float*    xns  = w4s + 512;                  // [128]

    const int tid  = threadIdx.x;
    const int bid  = blockIdx.x;
    const int n    = bid & 63;                   // same-node WGs -> same XCD
    const int tile = bid >> 6;                   // 0..7
    const int lane = tid & 63;
    const int pos  = lane & 15;
    const int quad = lane >> 4;
    const int wv   = __builtin_amdgcn_readfirstlane(tid >> 6);   // 0..3
    const int row0 = tile * 128;
    const int wrow = wv << 5;

    const _Float16* W1f  = (const _Float16*)ws + (size_t)n * 32768;
    const _Float16* W2f  = (const _Float16*)ws + 2097152 + (size_t)n * 32768;
    const _Float16* W3f  = (const _Float16*)ws + 4194304 + (size_t)n * 32768;
    const float*    w3cp = (const float*)(ws + 12582912) + n * 512;

    // ---- prologue: stage chunk 0 (W1,W2), scalars, xn, Xm A-frags ----
    {
        const _Float16* s1 = W1f + wv * 1024 + lane * 8;
        gld16(s1,       w1b + wv * 1024);
        gld16(s1 + 512, w1b + wv * 1024 + 512);
        const _Float16* s2 = W2f + wv * 1024 + lane * 8;
        gld16(s2,       w2b + wv * 1024);
        gld16(s2 + 512, w2b + wv * 1024 + 512);
    }
    #pragma unroll
    for (int k = 0; k < 2; ++k) {
        const int h = tid + k * 256;
        w3cs[h] = w3cp[h];
        b3s[h]  = b3[n * HH + h];
        w4s[h]  = W4[n * HH + h];
    }
    if (tid < 128) xns[tid] = x[(size_t)(row0 + tid) * NN + n];

    // Xm A-fragments (own element zeroed) — chunk-invariant
    h8 aX[2][2];
    #pragma unroll
    for (int mt = 0; mt < 2; ++mt)
        #pragma unroll
        for (int ks = 0; ks < 2; ++ks) {
            const float* p = x + (size_t)(row0 + wrow + mt * 16 + pos) * NN + ks * 32 + quad * 8;
            float4 a = *(const float4*)p, bq = *(const float4*)(p + 4);
            float v[8] = {a.x, a.y, a.z, a.w, bq.x, bq.y, bq.z, bq.w};
            const int base = ks * 32 + quad * 8;
            #pragma unroll
            for (int j = 0; j < 8; ++j) if (base + j == n) v[j] = 0.f;
            h8 h;
            #pragma unroll
            for (int j = 0; j < 8; ++j) h[j] = (_Float16)v[j];
            aX[mt][ks] = h;
        }
    __syncthreads();                              // drains prologue staging

    _Float16* P = priv + wv * 2304;               // own 32x72 buffer

    // ---- fused stages A+B over 8 h-chunks (dbuf staging overlaps MFMA) ----
    fx4 acc2[2][4] = {};
    for (int c = 0; c < 8; ++c) {
        const int cb = c & 1;
        if (c < 7) {                               // stage chunk c+1 into other buffer
            const _Float16* s1 = W1f + (c + 1) * 4096 + wv * 1024 + lane * 8;
            gld16(s1,       w1b + (cb ^ 1) * 4096 + wv * 1024);
            gld16(s1 + 512, w1b + (cb ^ 1) * 4096 + wv * 1024 + 512);
            const _Float16* s2 = W2f + (c + 1) * 4096 + wv * 1024 + lane * 8;
            gld16(s2,       w2b + (cb ^ 1) * 4096 + wv * 1024);
            gld16(s2 + 512, w2b + (cb ^ 1) * 4096 + wv * 1024 + 512);
        } else {                                   // stage W3 chunk 0 into w1b[0]
            const _Float16* s3 = W3f + wv * 1024 + lane * 8;
            gld16(s3,       w1b + wv * 1024);
            gld16(s3 + 512, w1b + wv * 1024 + 512);
        }
        // stage A: h1 chunk = Xm @ W1chunk^T  (frags lane-contiguous in LDS)
        const h8* F1 = (const h8*)(w1b + cb * 4096);
        fx4 accA[2][4] = {};
        #pragma unroll
        for (int ks = 0; ks < 2; ++ks)
            #pragma unroll
            for (int nt = 0; nt < 4; ++nt) {
                h8 bf = F1[(ks * 4 + nt) * 64 + lane];
                accA[0][nt] = MFMA(aX[0][ks], bf, accA[0][nt], 0, 0, 0);
                accA[1][nt] = MFMA(aX[1][ks], bf, accA[1][nt], 0, 0, 0);
            }
        // h1 -> own LDS (relu, fp16), read back as A-frags for stage B
        #pragma unroll
        for (int mt = 0; mt < 2; ++mt)
            #pragma unroll
            for (int nt = 0; nt < 4; ++nt)
                #pragma unroll
                for (int r = 0; r < 4; ++r)
                    P[(mt * 16 + quad * 4 + r) * 72 + nt * 16 + pos] =
                        (_Float16)fmaxf(accA[mt][nt][r], 0.f);
        h8 aH[2][2];
        #pragma unroll
        for (int mt = 0; mt < 2; ++mt)
            #pragma unroll
            for (int ks = 0; ks < 2; ++ks)
                aH[mt][ks] = *(const h8*)(P + (mt * 16 + pos) * 72 + ks * 32 + quad * 8);
        // stage B: acc2 += h1chunk @ W2chunk^T
        const h8* F2 = (const h8*)(w2b + cb * 4096);
        #pragma unroll
        for (int ks = 0; ks < 2; ++ks)
            #pragma unroll
            for (int cm = 0; cm < 4; ++cm) {
                h8 bf = F2[(ks * 4 + cm) * 64 + lane];
                acc2[0][cm] = MFMA(aH[0][ks], bf, acc2[0][cm], 0, 0, 0);
                acc2[1][cm] = MFMA(aH[1][ks], bf, acc2[1][cm], 0, 0, 0);
            }
        __syncthreads();                           // staging done + buffers free
    }

    // ---- r1 -> own LDS (relu), read back as A-frags ----
    #pragma unroll
    for (int mt = 0; mt < 2; ++mt)
        #pragma unroll
        for (int cm = 0; cm < 4; ++cm)
            #pragma unroll
            for (int r = 0; r < 4; ++r)
                P[(mt * 16 + quad * 4 + r) * 72 + cm * 16 + pos] =
                    (_Float16)fmaxf(acc2[mt][cm][r], 0.f);
    h8 aR[2][2];
    #pragma unroll
    for (int mt = 0; mt < 2; ++mt)
        #pragma unroll
        for (int ks = 0; ks < 2; ++ks)
            aR[mt][ks] = *(const h8*)(P + (mt * 16 + pos) * 72 + ks * 32 + quad * 8);
    // fold A-frag: k=64 -> xn, k=65 -> 1 (only quad 0 lanes carry data)
    h8 af3[2];
    #pragma unroll
    for (int mt = 0; mt < 2; ++mt) {
        h8 h;
        #pragma unroll
        for (int j = 0; j < 8; ++j) h[j] = (_Float16)0.f;
        if (quad == 0) { h[0] = (_Float16)xns[wrow + mt * 16 + pos]; h[1] = (_Float16)1.f; }
        af3[mt] = h;
    }

    // ---- stage C/D over 8 h-chunks: W3 frags staged into w1b dbuf ----
    float o[2][4] = {};
    for (int c = 0; c < 8; ++c) {
        const int cb = c & 1;
        const int hc = c << 6;
        if (c < 7) {
            const _Float16* s3 = W3f + (c + 1) * 4096 + wv * 1024 + lane * 8;
            gld16(s3,       w1b + (cb ^ 1) * 4096 + wv * 1024);
            gld16(s3 + 512, w1b + (cb ^ 1) * 4096 + wv * 1024 + 512);
        }
        const h8* F3 = (const h8*)(w1b + cb * 4096);
        fx4 acc3[2][4] = {};
        #pragma unroll
        for (int ks = 0; ks < 2; ++ks)
            #pragma unroll
            for (int nt = 0; nt < 4; ++nt) {
                h8 bf = F3[(ks * 4 + nt) * 64 + lane];
                acc3[0][nt] = MFMA(aR[0][ks], bf, acc3[0][nt], 0, 0, 0);
                acc3[1][nt] = MFMA(aR[1][ks], bf, acc3[1][nt], 0, 0, 0);
            }
        // fold: += [xn,1] @ [w3c; b3]
        #pragma unroll
        for (int nt = 0; nt < 4; ++nt) {
            h8 bf3;
            #pragma unroll
            for (int j = 0; j < 8; ++j) bf3[j] = (_Float16)0.f;
            if (quad == 0) {
                const int h = hc + nt * 16 + pos;
                bf3[0] = (_Float16)w3cs[h];
                bf3[1] = (_Float16)b3s[h];
            }
            acc3[0][nt] = MFMA(af3[0], bf3, acc3[0][nt], 0, 0, 0);
            acc3[1][nt] = MFMA(af3[1], bf3, acc3[1][nt], 0, 0, 0);
        }
        // relu + W4 dot
        #pragma unroll
        for (int nt = 0; nt < 4; ++nt) {
            const float w4v = w4s[hc + nt * 16 + pos];
            #pragma unroll
            for (int mt = 0; mt < 2; ++mt)
                #pragma unroll
                for (int r = 0; r < 4; ++r)
                    o[mt][r] = fmaf(fmaxf(acc3[mt][nt][r], 0.f), w4v, o[mt][r]);
        }
        __syncthreads();
    }

    // ---- reduce over the 16 h-columns (pos bits), store ----
    #pragma unroll
    for (int m = 1; m < 16; m <<= 1)
        #pragma unroll
        for (int mt = 0; mt < 2; ++mt)
            #pragma unroll
            for (int r = 0; r < 4; ++r)
                o[mt][r] += __shfl_xor(o[mt][r], m, 64);

    if (pos == 0) {
        const float bb = b4[n];
        #pragma unroll
        for (int mt = 0; mt < 2; ++mt)
            #pragma unroll
            for (int r = 0; r < 4; ++r) {
                const int row = row0 + wrow + mt * 16 + quad * 4 + r;
                out[(size_t)row * 64 + n] = fmaxf(o[mt][r] + bb, 0.f);
            }
    }
}

// ---------------------------------------------------------------------------
// Legacy fallback (proven 112 µs kernel) — used only if ws is too small.
// ---------------------------------------------------------------------------
__device__ __forceinline__ void cvt_store16(_Float16* d, const float4* p) {
    h8 h0, h1;
    h0[0]=(_Float16)p[0].x; h0[1]=(_Float16)p[0].y; h0[2]=(_Float16)p[0].z; h0[3]=(_Float16)p[0].w;
    h0[4]=(_Float16)p[1].x; h0[5]=(_Float16)p[1].y; h0[6]=(_Float16)p[1].z; h0[7]=(_Float16)p[1].w;
    h1[0]=(_Float16)p[2].x; h1[1]=(_Float16)p[2].y; h1[2]=(_Float16)p[2].z; h1[3]=(_Float16)p[2].w;
    h1[4]=(_Float16)p[3].x; h1[5]=(_Float16)p[3].y; h1[6]=(_Float16)p[3].z; h1[7]=(_Float16)p[3].w;
    *(h8*)d = h0; *((h8*)d + 1) = h1;
}

__global__ __launch_bounds__(256, 2)
void causal_mfma3(const float* __restrict__ x,  const float* __restrict__ W1,
                  const float* __restrict__ W2, const float* __restrict__ W3,
                  const float* __restrict__ b3, const float* __restrict__ W4,
                  const float* __restrict__ b4, float* __restrict__ out)
{
    __shared__ __align__(16) char smem[61952];
    _Float16* W1c  = (_Float16*)smem;
    _Float16* W2c  = W1c + 2 * 4608;
    _Float16* priv = W2c + 2 * 4608;
    float*    w3cs = (float*)(smem + 55296);
    float*    b3s  = w3cs + 512;
    float*    w4s  = b3s + 512;
    float*    xns  = w4s + 512;

    const int tid  = threadIdx.x;
    const int bid  = blockIdx.x;
    const int n    = bid & 63;
    const int tile = bid >> 6;
    const int lane = tid & 63;
    const int pos  = lane & 15;
    const int quad = lane >> 4;
    const int wv   = __builtin_amdgcn_readfirstlane(tid >> 6);
    const int row0 = tile * 128;
    const int wrow = wv << 5;

    const float* W1n = W1 + (size_t)n * HH * NN;
    const float* W2n = W2 + (size_t)n * NN * HH;
    const float* W3n = W3 + (size_t)n * HH * 128;

    const int trow = tid >> 2;
    const int tcol = (tid & 3) << 4;

    {
        float4 p1[4], p2[4];
        #pragma unroll
        for (int q = 0; q < 4; ++q) p1[q] = *(const float4*)(W1n + trow * 64 + tcol + q * 4);
        #pragma unroll
        for (int q = 0; q < 4; ++q) p2[q] = *(const float4*)(W2n + (size_t)trow * HH + tcol + q * 4);
        #pragma unroll
        for (int k = 0; k < 2; ++k) {
            const int h = tid + k * 256;
            w3cs[h] = W3n[(size_t)h * 128 + 64 + n];
            b3s[h]  = b3[n * HH + h];
            w4s[h]  = W4[n * HH + h];
        }
        if (tid < 128) xns[tid] = x[(size_t)(row0 + tid) * NN + n];
        cvt_store16(W1c + trow * 72 + tcol, p1);
        cvt_store16(W2c + trow * 72 + tcol, p2);
    }

    h8 aX[2][2];
    #pragma unroll
    for (int mt = 0; mt < 2; ++mt)
        #pragma unroll
        for (int ks = 0; ks < 2; ++ks) {
            const float* p = x + (size_t)(row0 + wrow + mt * 16 + pos) * NN + ks * 32 + quad * 8;
            float4 a = *(const float4*)p, bq = *(const float4*)(p + 4);
            float v[8] = {a.x, a.y, a.z, a.w, bq.x, bq.y, bq.z, bq.w};
            const int base = ks * 32 + quad * 8;
            #pragma unroll
            for (int j = 0; j < 8; ++j) if (base + j == n) v[j] = 0.f;
            h8 h;
            #pragma unroll
            for (int j = 0; j < 8; ++j) h[j] = (_Float16)v[j];
            aX[mt][ks] = h;
        }
    __syncthreads();

    _Float16* P = priv + wv * 2304;

    fx4 acc2[2][4] = {};
    for (int c = 0; c < 8; ++c) {
        const int cb = c & 1;
        float4 p1[4], p2[4];
        if (c < 7) {
            const int hb1 = (c + 1) << 6;
            #pragma unroll
            for (int q = 0; q < 4; ++q) p1[q] = *(const float4*)(W1n + (hb1 + trow) * 64 + tcol + q * 4);
            #pragma unroll
            for (int q = 0; q < 4; ++q) p2[q] = *(const float4*)(W2n + (size_t)trow * HH + hb1 + tcol + q * 4);
        }
        const _Float16* W1L = W1c + cb * 4608;
        fx4 accA[2][4] = {};
        #pragma unroll
        for (int ks = 0; ks < 2; ++ks)
            #pragma unroll
            for (int nt = 0; nt < 4; ++nt) {
                h8 bf = *(const h8*)(W1L + (nt * 16 + pos) * 72 + ks * 32 + quad * 8);
                accA[0][nt] = MFMA(aX[0][ks], bf, accA[0][nt], 0, 0, 0);
                accA[1][nt] = MFMA(aX[1][ks], bf, accA[1][nt], 0, 0, 0);
            }
        #pragma unroll
        for (int mt = 0; mt < 2; ++mt)
            #pragma unroll
            for (int nt = 0; nt < 4; ++nt)
                #pragma unroll
                for (int r = 0; r < 4; ++r)
                    P[(mt * 16 + quad * 4 + r) * 72 + nt * 16 + pos] =
                        (_Float16)fmaxf(accA[mt][nt][r], 0.f);
        h8 aH[2][2];
        #pragma unroll
        for (int mt = 0; mt < 2; ++mt)
            #pragma unroll
            for (int ks = 0; ks < 2; ++ks)
                aH[mt][ks] = *(const h8*)(P + (mt * 16 + pos) * 72 + ks * 32 + quad * 8);
        const _Float16* W2L = W2c + cb * 4608;
        #pragma unroll
        for (int ks = 0; ks < 2; ++ks)
            #pragma unroll
            for (int cm = 0; cm < 4; ++cm) {
                h8 bf = *(const h8*)(W2L + (cm * 16 + pos) * 72 + ks * 32 + quad * 8);
                acc2[0][cm] = MFMA(aH[0][ks], bf, acc2[0][cm], 0, 0, 0);
                acc2[1][cm] = MFMA(aH[1][ks], bf, acc2[1][cm], 0, 0, 0);
            }
        if (c < 7) {
            cvt_store16(W1c + (cb ^ 1) * 4608 + trow * 72 + tcol, p1);
            cvt_store16(W2c + (cb ^ 1) * 4608 + trow * 72 + tcol, p2);
        }
        __syncthreads();
    }

    #pragma unroll
    for (int mt = 0; mt < 2; ++mt)
        #pragma unroll
        for (int cm = 0; cm < 4; ++cm)
            #pragma unroll
            for (int r = 0; r < 4; ++r)
                P[(mt * 16 + quad * 4 + r) * 72 + cm * 16 + pos] =
                    (_Float16)fmaxf(acc2[mt][cm][r], 0.f);
    h8 aR[2][2];
    #pragma unroll
    for (int mt = 0; mt < 2; ++mt)
        #pragma unroll
        for (int ks = 0; ks < 2; ++ks)
            aR[mt][ks] = *(const h8*)(P + (mt * 16 + pos) * 72 + ks * 32 + quad * 8);
    h8 af3[2];
    #pragma unroll
    for (int mt = 0; mt < 2; ++mt) {
        h8 h;
        #pragma unroll
        for (int j = 0; j < 8; ++j) h[j] = (_Float16)0.f;
        if (quad == 0) { h[0] = (_Float16)xns[wrow + mt * 16 + pos]; h[1] = (_Float16)1.f; }
        af3[mt] = h;
    }

    {
        float4 p3[4];
        #pragma unroll
        for (int q = 0; q < 4; ++q) p3[q] = *(const float4*)(W3n + (size_t)trow * 128 + tcol + q * 4);
        cvt_store16(W1c + trow * 72 + tcol, p3);
    }
    __syncthreads();

    float o[2][4] = {};
    for (int c = 0; c < 8; ++c) {
        const int cb = c & 1;
        const int hc = c << 6;
        float4 p3[4];
        if (c < 7) {
            #pragma unroll
            for (int q = 0; q < 4; ++q)
                p3[q] = *(const float4*)(W3n + (size_t)(hc + 64 + trow) * 128 + tcol + q * 4);
        }
        const _Float16* W3L = W1c + cb * 4608;
        fx4 acc3[2][4] = {};
        #pragma unroll
        for (int ks = 0; ks < 2; ++ks)
            #pragma unroll
            for (int nt = 0; nt < 4; ++nt) {
                h8 bf = *(const h8*)(W3L + (nt * 16 + pos) * 72 + ks * 32 + quad * 8);
                acc3[0][nt] = MFMA(aR[0][ks], bf, acc3[0][nt], 0, 0, 0);
                acc3[1][nt] = MFMA(aR[1][ks], bf, acc3[1][nt], 0, 0, 0);
            }
        #pragma unroll
        for (int nt = 0; nt < 4; ++nt) {
            h8 bf3;
            #pragma unroll
            for (int j = 0; j < 8; ++j) bf3[j] = (_Float16)0.f;
            if (quad == 0) {
                const int h = hc + nt * 16 + pos;
                bf3[0] = (_Float16)w3cs[h];
                bf3[1] = (_Float16)b3s[h];
            }
            acc3[0][nt] = MFMA(af3[0], bf3, acc3[0][nt], 0, 0, 0);
            acc3[1][nt] = MFMA(af3[1], bf3, acc3[1][nt], 0, 0, 0);
        }
        #pragma unroll
        for (int nt = 0; nt < 4; ++nt) {
            const float w4v = w4s[hc + nt * 16 + pos];
            #pragma unroll
            for (int mt = 0; mt < 2; ++mt)
                #pragma unroll
                for (int r = 0; r < 4; ++r)
                    o[mt][r] = fmaf(fmaxf(acc3[mt][nt][r], 0.f), w4v, o[mt][r]);
        }
        if (c < 7) cvt_store16(W1c + (cb ^ 1) * 4608 + trow * 72 + tcol, p3);
        __syncthreads();
    }

    #pragma unroll
    for (int m = 1; m < 16; m <<= 1)
        #pragma unroll
        for (int mt = 0; mt < 2; ++mt)
            #pragma unroll
            for (int r = 0; r < 4; ++r)
                o[mt][r] += __shfl_xor(o[mt][r], m, 64);

    if (pos == 0) {
        const float bb = b4[n];
        #pragma unroll
        for (int mt = 0; mt < 2; ++mt)
            #pragma unroll
            for (int r = 0; r < 4; ++r) {
                const int row = row0 + wrow + mt * 16 + quad * 4 + r;
                out[(size_t)row * 64 + n] = fmaxf(o[mt][r] + bb, 0.f);
            }
    }
}

extern "C" void kernel_launch(void* const* d_in, const int* in_sizes, int n_in,
                              void* d_out, int out_size, void* d_ws, size_t ws_size,
                              hipStream_t stream)
{
    const float* x  = (const float*)d_in[0];
    const float* W1 = (const float*)d_in[1];
    const float* W2 = (const float*)d_in[2];
    const float* W3 = (const float*)d_in[3];
    const float* b3 = (const float*)d_in[4];
    const float* W4 = (const float*)d_in[5];
    const float* b4 = (const float*)d_in[6];
    float* out = (float*)d_out;

    if (d_ws != nullptr && ws_size >= WS_NEEDED) {
        hipLaunchKernelGGL(cvt_frag, dim3(1024), dim3(256), 0, stream,
                           W1, W2, W3, (char*)d_ws);
        hipLaunchKernelGGL(causal_mfma5, dim3(512), dim3(256), 0, stream,
                           x, (const char*)d_ws, b3, W4, b4, out);
    } else {
        hipLaunchKernelGGL(causal_mfma3, dim3(512), dim3(256), 0, stream,
                           x, W1, W2, W3, b3, W4, b4, out);
    }
}